// Round 3
// baseline (613.676 us; speedup 1.0000x reference)
//
#include <hip/hip_runtime.h>
#include <math.h>

#define N_TOK 32768
#define M_EMB 1024
#define D_DIM 128

// workspace layout (bytes)
#define WS_EH  0                        // bf16 e_hi[1024][128]   (256 KB)
#define WS_EL  262144                   // bf16 e_lo[1024][128]   (256 KB)
#define WS_TH  524288                   // bf16 et_hi[128][1024]  (256 KB)
#define WS_TL  786432                   // bf16 et_lo[128][1024]  (256 KB)
#define WS_E2  1048576                  // float e2[1024]
#define WS_CNT (WS_E2 + 4096)           // int counts[1024]
#define WS_SS  (WS_CNT + 4096)          // float sum((x-q)^2)
#define WS_ENT (WS_SS + 4)              // float sum(p*logp)

typedef float  f32x4  __attribute__((ext_vector_type(4)));
typedef short  s16x8  __attribute__((ext_vector_type(8)));
typedef short  s16x4  __attribute__((ext_vector_type(4)));
typedef __bf16 bf16x8 __attribute__((ext_vector_type(8)));

__device__ __forceinline__ ushort f2bf(float f) {
    unsigned x = __float_as_uint(f);
    unsigned r = (x + 0x7fffu + ((x >> 16) & 1u)) >> 16;
    return (ushort)r;
}
__device__ __forceinline__ float bf2f(ushort h) {
    return __uint_as_float(((unsigned)h) << 16);
}
__device__ __forceinline__ f32x4 mfma_k32(s16x8 a, s16x8 b, f32x4 c) {
    return __builtin_amdgcn_mfma_f32_16x16x32_bf16(
        __builtin_bit_cast(bf16x8, a), __builtin_bit_cast(bf16x8, b), c, 0, 0, 0);
}
__device__ __forceinline__ f32x4 mfma_k16(s16x4 a, s16x4 b, f32x4 c) {
#if __has_builtin(__builtin_amdgcn_mfma_f32_16x16x16bf16_1k)
    return __builtin_amdgcn_mfma_f32_16x16x16bf16_1k(a, b, c, 0, 0, 0);
#else
    asm("v_mfma_f32_16x16x16_bf16 %0, %1, %2, %0" : "+v"(c) : "v"(a), "v"(b));
    return c;
#endif
}

// Convert embedding to bf16 hi/lo in row-major and transposed layouts; e2; zero accums.
__global__ void k_prep(const float* __restrict__ emb, char* ws) {
    __shared__ ushort th_s[16][128];
    __shared__ ushort tl_s[16][128];
    if (blockIdx.x == 0) {
        int* cnt = (int*)(ws + WS_CNT);
        for (int i = threadIdx.x; i < M_EMB; i += 256) cnt[i] = 0;
        if (threadIdx.x == 0) {
            *(float*)(ws + WS_SS) = 0.f;
            *(float*)(ws + WS_ENT) = 0.f;
        }
    }
    ushort* eh = (ushort*)(ws + WS_EH);
    ushort* el = (ushort*)(ws + WS_EL);
    ushort* th = (ushort*)(ws + WS_TH);
    ushort* tl = (ushort*)(ws + WS_TL);
    float* e2 = (float*)(ws + WS_E2);
    const int m0 = blockIdx.x * 16;
    const int t = threadIdx.x;
    #pragma unroll
    for (int ii = 0; ii < 8; ii++) {
        int idx = t + ii * 256;          // 0..2047
        int mi = idx >> 7, k = idx & 127;
        float v = emb[(size_t)(m0 + mi) * D_DIM + k];
        ushort hi = f2bf(v);
        ushort lo = f2bf(v - bf2f(hi));
        eh[(size_t)(m0 + mi) * D_DIM + k] = hi;
        el[(size_t)(m0 + mi) * D_DIM + k] = lo;
        th_s[mi][k] = hi;
        tl_s[mi][k] = lo;
    }
    __syncthreads();
    {
        int k = t >> 1, half = t & 1;
        s16x8 vh, vl;
        #pragma unroll
        for (int j = 0; j < 8; j++) {
            vh[j] = (short)th_s[half * 8 + j][k];
            vl[j] = (short)tl_s[half * 8 + j][k];
        }
        *(s16x8*)(th + (size_t)k * M_EMB + m0 + half * 8) = vh;
        *(s16x8*)(tl + (size_t)k * M_EMB + m0 + half * 8) = vl;
    }
    if (t < 16) {
        float s = 0.f;
        const float* er = emb + (size_t)(m0 + t) * D_DIM;
        #pragma unroll 4
        for (int k = 0; k < 128; k++) s += er[k] * er[k];
        e2[m0 + t] = s;
    }
}

// Flash-style fused kernel: each wave owns 32 rows, streams m in 32-chunks.
// No LDS, no block barriers. Scores land at lane layout (m=4h+j, n=l15) which
// IS the A-fragment layout of mfma_16x16x16_bf16 -> PV feeds directly from regs.
__global__ __launch_bounds__(128, 2) void k_main(
    const float* __restrict__ x, const float* __restrict__ emb,
    const float* __restrict__ lvq, const float* __restrict__ u,
    float* __restrict__ out, char* __restrict__ ws)
{
    const int t = threadIdx.x;
    const int w = t >> 6;
    const int lane = t & 63;
    const int l15 = lane & 15;
    const int h = lane >> 4;
    const int n0 = (blockIdx.x * 2 + w) * 32;

    const float* e2g = (const float*)(ws + WS_E2);
    int* cnt = (int*)(ws + WS_CNT);
    float* ws_ss = (float*)(ws + WS_SS);
    float* ws_ent = (float*)(ws + WS_ENT);
    const s16x8* EH = (const s16x8*)(ws + WS_EH);
    const s16x8* EL = (const s16x8*)(ws + WS_EL);
    const s16x4* TH4 = (const s16x4*)(ws + WS_TH);
    const s16x4* TL4 = (const s16x4*)(ws + WS_TL);

    const float prec = expf(-lvq[0]);
    const float hp = 0.5f * prec;

    // ---- x B-fragments (rows n0 + rt*16 + l15), split hi/lo ----
    s16x8 xh[2][4], xl[2][4];
    #pragma unroll
    for (int rt = 0; rt < 2; rt++) {
        const float* xr = x + (size_t)(n0 + rt * 16 + l15) * D_DIM;
        #pragma unroll
        for (int ks = 0; ks < 4; ks++) {
            const int k0 = ks * 32 + h * 8;
            float4 v0 = *(const float4*)(xr + k0);
            float4 v1 = *(const float4*)(xr + k0 + 4);
            float vv[8] = {v0.x, v0.y, v0.z, v0.w, v1.x, v1.y, v1.z, v1.w};
            s16x8 hi8, lo8;
            #pragma unroll
            for (int j = 0; j < 8; j++) {
                ushort hi = f2bf(vv[j]);
                hi8[j] = (short)hi;
                lo8[j] = (short)f2bf(vv[j] - bf2f(hi));
            }
            xh[rt][ks] = hi8;
            xl[rt][ks] = lo8;
        }
    }

    const f32x4 zz = {0.f, 0.f, 0.f, 0.f};
    f32x4 qacc[2][8];
    #pragma unroll
    for (int rt = 0; rt < 2; rt++)
        #pragma unroll
        for (int dt = 0; dt < 8; dt++) qacc[rt][dt] = zz;

    float S[2] = {0.f, 0.f}, T[2] = {0.f, 0.f}, Sg[2] = {0.f, 0.f};
    float bv1[2] = {-INFINITY, -INFINITY}, bv2[2] = {-INFINITY, -INFINITY};
    int bi1[2] = {M_EMB, M_EMB}, bi2[2] = {M_EMB, M_EMB};

    const float* urow[2] = {u + (size_t)(n0 + l15) * M_EMB,
                            u + (size_t)(n0 + 16 + l15) * M_EMB};
    const float EPS = 1.1920929e-07f, OME = 0.99999988f;

    #pragma unroll 1
    for (int mc = 0; mc < 32; mc++) {
        const int mb = mc * 32;
        // hoist the HBM-latency u loads for this whole chunk ahead of the MFMAs
        float4 uvv[2][2];
        #pragma unroll
        for (int t2 = 0; t2 < 2; t2++)
            #pragma unroll
            for (int rt = 0; rt < 2; rt++)
                uvv[t2][rt] = *(const float4*)(urow[rt] + mb + t2 * 16 + h * 4);
        #pragma unroll
        for (int t2 = 0; t2 < 2; t2++) {
            const int msub = mb + t2 * 16;
            // A-fragments: E rows (msub + l15), shared across both n-tiles
            s16x8 ah[4], al[4];
            #pragma unroll
            for (int ks = 0; ks < 4; ks++) {
                const int bidx = (msub + l15) * 16 + ks * 4 + h;
                ah[ks] = EH[bidx];
                al[ks] = EL[bidx];
            }
            // scores: D[m = 4h+j][n = l15] per rt, 3-way bf16 split
            f32x4 sc[2];
            #pragma unroll
            for (int rt = 0; rt < 2; rt++) {
                f32x4 aa = zz, ab = zz, ac = zz;
                #pragma unroll
                for (int ks = 0; ks < 4; ks++) {
                    aa = mfma_k32(ah[ks], xh[rt][ks], aa);
                    ab = mfma_k32(al[ks], xh[rt][ks], ab);
                    ac = mfma_k32(ah[ks], xl[rt][ks], ac);
                }
                #pragma unroll
                for (int j = 0; j < 4; j++) sc[rt][j] = aa[j] + ab[j] + ac[j];
            }
            const float4 e2v = *(const float4*)(e2g + msub + h * 4);
            #pragma unroll
            for (int rt = 0; rt < 2; rt++) {
                const float uu[4] = {uvv[t2][rt].x, uvv[t2][rt].y, uvv[t2][rt].z, uvv[t2][rt].w};
                const float ee[4] = {e2v.x, e2v.y, e2v.z, e2v.w};
                ushort pb[4];
                #pragma unroll
                for (int j = 0; j < 4; j++) {
                    const int m = msub + h * 4 + j;
                    const float v = prec * sc[rt][j] - hp * ee[j];
                    // top-2 (ascending m within lane)
                    if (v > bv1[rt]) {
                        bv2[rt] = bv1[rt]; bi2[rt] = bi1[rt];
                        bv1[rt] = v; bi1[rt] = m;
                    } else if (v > bv2[rt]) {
                        bv2[rt] = v; bi2[rt] = m;
                    }
                    // entropy sums (no max shift needed: |v| <~ 40)
                    const float e = __expf(v);
                    S[rt] += e; T[rt] += e * v;
                    // gumbel: p~ = exp(v + g) = e / (-log u)
                    const float uc = fminf(fmaxf(uu[j], EPS), OME);
                    const float d1 = 1.0f - uc;
                    const float Lser = d1 * (1.0f + d1 * (0.5f + d1 * (0.33333334f + d1 * 0.25f)));
                    const float Lnat = -__logf(uc);
                    const float L = (d1 < 0.03125f) ? Lser : Lnat;
                    const float pt = e * __builtin_amdgcn_rcpf(L);
                    Sg[rt] += pt;
                    pb[j] = f2bf(pt);
                }
                // PV: p~ tile is already in mfma_16x16x16 A-layout (row n=l15, k=4h+j)
                s16x4 pa;
                pa[0] = (short)pb[0]; pa[1] = (short)pb[1];
                pa[2] = (short)pb[2]; pa[3] = (short)pb[3];
                const int bbase = l15 * 256 + (mb >> 2) + t2 * 4 + h;
                #pragma unroll
                for (int dt = 0; dt < 8; dt++) {
                    const int bidx = dt * 4096 + bbase;
                    qacc[rt][dt] = mfma_k16(pa, TH4[bidx], qacc[rt][dt]);
                    qacc[rt][dt] = mfma_k16(pa, TL4[bidx], qacc[rt][dt]);
                }
            }
        }
    }

    // ---- reduce per-row stats across h-group (lanes l, l^16, l^32, l^48) ----
    #pragma unroll
    for (int rt = 0; rt < 2; rt++) {
        #pragma unroll
        for (int off = 16; off <= 32; off <<= 1) {
            S[rt] += __shfl_xor(S[rt], off);
            T[rt] += __shfl_xor(T[rt], off);
            Sg[rt] += __shfl_xor(Sg[rt], off);
            const float ov1 = __shfl_xor(bv1[rt], off); const int oi1 = __shfl_xor(bi1[rt], off);
            const float ov2 = __shfl_xor(bv2[rt], off); const int oi2 = __shfl_xor(bi2[rt], off);
            if (ov1 > bv1[rt] || (ov1 == bv1[rt] && oi1 < bi1[rt])) {
                if (bv1[rt] > ov2 || (bv1[rt] == ov2 && bi1[rt] < oi2)) { bv2[rt] = bv1[rt]; bi2[rt] = bi1[rt]; }
                else { bv2[rt] = ov2; bi2[rt] = oi2; }
                bv1[rt] = ov1; bi1[rt] = oi1;
            } else if (ov1 > bv2[rt] || (ov1 == bv2[rt] && oi1 < bi2[rt])) {
                bv2[rt] = ov1; bi2[rt] = oi1;
            }
        }
    }

    // ---- entropy: every lane holds full-row S,T (x4 dup) -> wave sum * 0.25 ----
    {
        float ent = (T[0] / S[0] - __logf(S[0])) + (T[1] / S[1] - __logf(S[1]));
        #pragma unroll
        for (int off = 1; off <= 32; off <<= 1) ent += __shfl_xor(ent, off);
        if (lane == 0) atomicAdd(ws_ent, 0.25f * ent);
    }

    // ---- exact fp32 recheck of top-2 candidates; write indices ----
    #pragma unroll
    for (int rt = 0; rt < 2; rt++) {
        const float* xr = x + (size_t)(n0 + rt * 16 + l15) * D_DIM + h * 32;
        const float* ea = emb + (size_t)bi1[rt] * D_DIM + h * 32;
        const float* eb = emb + (size_t)bi2[rt] * D_DIM + h * 32;
        float s1 = 0.f, s2 = 0.f;
        #pragma unroll
        for (int i = 0; i < 8; i++) {
            const float4 xv = ((const float4*)xr)[i];
            const float4 av = ((const float4*)ea)[i];
            const float4 bb = ((const float4*)eb)[i];
            s1 += xv.x * av.x + xv.y * av.y + xv.z * av.z + xv.w * av.w;
            s2 += xv.x * bb.x + xv.y * bb.y + xv.z * bb.z + xv.w * bb.w;
        }
        #pragma unroll
        for (int off = 16; off <= 32; off <<= 1) {
            s1 += __shfl_xor(s1, off);
            s2 += __shfl_xor(s2, off);
        }
        const float g1 = prec * s1 - hp * e2g[bi1[rt]];
        const float g2 = prec * s2 - hp * e2g[bi2[rt]];
        const int win = (g2 > g1 || (g2 == g1 && bi2[rt] < bi1[rt])) ? bi2[rt] : bi1[rt];
        if (lane < 16) {
            out[(size_t)N_TOK * D_DIM + n0 + rt * 16 + lane] = (float)win;
            atomicAdd(&cnt[win], 1);
        }
    }

    // ---- PV epilogue: q = qacc / Sg; write out; sum (x-q)^2 ----
    float ssl = 0.f;
    #pragma unroll
    for (int rt = 0; rt < 2; rt++) {
        float inv[4];
        #pragma unroll
        for (int j = 0; j < 4; j++) {
            const float sgv = __shfl(Sg[rt], 4 * h + j);
            inv[j] = 1.0f / sgv;
        }
        #pragma unroll
        for (int dt = 0; dt < 8; dt++) {
            #pragma unroll
            for (int j = 0; j < 4; j++) {
                const int n = n0 + rt * 16 + 4 * h + j;
                const int d = dt * 16 + l15;
                const float q = qacc[rt][dt][j] * inv[j];
                out[(size_t)n * D_DIM + d] = q;
                const float df = x[(size_t)n * D_DIM + d] - q;
                ssl += df * df;
            }
        }
    }
    #pragma unroll
    for (int off = 1; off <= 32; off <<= 1) ssl += __shfl_xor(ssl, off);
    if (lane == 0) atomicAdd(ws_ss, ssl);
}

__global__ void k_final(const float* __restrict__ lvq, float* __restrict__ out, char* ws) {
    const int* cnt = (const int*)(ws + WS_CNT);
    float s = 0.f;
    for (int i = threadIdx.x; i < M_EMB; i += 256) {
        float avg = (float)cnt[i] * (1.f / N_TOK);
        s += avg * logf(avg + 1e-10f);
    }
    #pragma unroll
    for (int off = 32; off >= 1; off >>= 1) s += __shfl_down(s, off);
    __shared__ float p[4];
    if ((threadIdx.x & 63) == 0) p[threadIdx.x >> 6] = s;
    __syncthreads();
    if (threadIdx.x == 0) {
        float tot = p[0] + p[1] + p[2] + p[3];
        float perp = expf(-tot);
        float prec = expf(-lvq[0]);
        float loss = 0.5f * prec * (*(float*)(ws + WS_SS)) + (*(float*)(ws + WS_ENT));
        out[(size_t)N_TOK * D_DIM + N_TOK] = loss;
        out[(size_t)N_TOK * D_DIM + N_TOK + 1] = perp;
    }
}

extern "C" void kernel_launch(void* const* d_in, const int* in_sizes, int n_in,
                              void* d_out, int out_size, void* d_ws, size_t ws_size,
                              hipStream_t stream) {
    const float* x   = (const float*)d_in[0];
    const float* emb = (const float*)d_in[1];
    const float* lvq = (const float*)d_in[2];
    const float* u   = (const float*)d_in[3];
    float* out = (float*)d_out;
    char* ws = (char*)d_ws;
    k_prep<<<dim3(M_EMB / 16), dim3(256), 0, stream>>>(emb, ws);
    k_main<<<dim3(N_TOK / 64), dim3(128), 0, stream>>>(x, emb, lvq, u, out, ws);
    k_final<<<dim3(1), dim3(256), 0, stream>>>(lvq, out, ws);
}